// Round 16
// baseline (2264.660 us; speedup 1.0000x reference)
//
#include <hip/hip_runtime.h>
#include <math.h>

// BiometricLSTM: 2-layer LSTM, B=512, T=2048, I=3, H=64, fp32 in/out. Output = final h2 (B,64).
//
// R16: balanced merged waves (R14's cheapest-per-seq stream) x 2 blocks/CU
// (R15's co-residency), minus R15's redundancy excess.
// Two-axis model from R13/R14/R15: wall = max(per-SIMD issue, chain/hiding).
//   R13: low issue, 2 w/SIMD, latency-bound 1630 cyc/iter.
//   R14: lowest stream, 1 w/SIMD -> exposed, 2120 cyc/iter.
//   R15: 4 w/SIMD but 4x redundant issue -> saturated, 2680 cyc/iter.
// This: R14 stream (24 MFMA, ONE barrier, 4-wave block) at M=1, 512 blocks ->
// 2 blocks/CU -> 2 waves/SIMD; per-SIMD issue ~2x572=1144 cyc worst case with
// real latency hiding. Diet: bias folded into MFMA C-operand, no sel4 (M=1:
// all C/D regs equal -> read reg 0), straight x loads. Numerics identical to
// R13/R14/R15 (f16 weights+h, f32 accum) -> absmax expected 4.882812e-4 exactly.
//
// 512 blocks x 256 threads (4 waves), 1 seq/block. Wave w owns gate-cols
// [16w,16w+16) of all 4 classes, BOTH layers (8 L0-MFMA + 16 L1-MFMA, balanced).
// Parity/lag-1 (R12-proven): iter it = L0 step it (uses h1[it-1]@prev) + L1 step
// it-1 (uses h1[it-1]@prev, h2[it-2]@cur); writes h1[it]->cur, h2[it-1]->prev.

typedef _Float16 half8 __attribute__((ext_vector_type(8)));
typedef float    f32x4 __attribute__((ext_vector_type(4)));

constexpr int TT = 2048;

__device__ __forceinline__ float fast_sigmoid(float x) {
    return 1.0f / (1.0f + __expf(-x));
}
// tanh = 1 - 2/(exp(2x)+1): saturates correctly at +-inf
__device__ __forceinline__ float fast_tanh(float x) {
    return 1.0f - 2.0f / (__expf(2.0f * x) + 1.0f);
}

__global__ __launch_bounds__(256) void lstm2_fused(
    const float* __restrict__ x,
    const float* __restrict__ Wih0, const float* __restrict__ Whh0,
    const float* __restrict__ bih0, const float* __restrict__ bhh0,
    const float* __restrict__ Wih1, const float* __restrict__ Whh1,
    const float* __restrict__ bih1, const float* __restrict__ bhh1,
    float* __restrict__ out)
{
    __shared__ __align__(16) _Float16 h1a[2][64];   // [parity][elem], single seq
    __shared__ __align__(16) _Float16 h2a[2][64];

    const int tid  = threadIdx.x;
    const int lane = tid & 63;
    const int wid  = tid >> 6;
    const int quad = lane >> 4;
    const int l16  = lane & 15;
    const int col  = wid * 16 + l16;     // this lane's gate-elem column (0..63)

    // ---- zero h double-buffers (256 halves) ----
    if (tid < 256) {
        ((_Float16*)h1a)[tid & 127] = (_Float16)0.0f;
        ((_Float16*)h2a)[tid & 127] = (_Float16)0.0f;
    }

    // ---- weights (B-fragments, f16): lane holds W[c*64+col][f*32 + quad*8 .. +8] ----
    half8 w0[4][2];     // L0: Whh0
    half8 w1[4][4];     // L1: [Wih1 | Whh1] over K=128
    f32x4 cb0[4], cb1[4];                // bias splats, used as MFMA C-input
    float wxa[4], wxb[4], wxc[4];
    #pragma unroll
    for (int c = 0; c < 4; ++c) {
        const int row = c * 64 + col;
        #pragma unroll
        for (int f = 0; f < 2; ++f) {
            const float* p = Whh0 + (size_t)row * 64 + f * 32 + quad * 8;
            half8 h;
            #pragma unroll
            for (int u = 0; u < 8; ++u) h[u] = (_Float16)p[u];
            w0[c][f] = h;
        }
        #pragma unroll
        for (int f = 0; f < 4; ++f) {
            const float* base = (f < 2) ? Wih1 : Whh1;
            const float* p = base + (size_t)row * 64 + (f & 1) * 32 + quad * 8;
            half8 h;
            #pragma unroll
            for (int u = 0; u < 8; ++u) h[u] = (_Float16)p[u];
            w1[c][f] = h;
        }
        const float b0 = bih0[row] + bhh0[row];
        const float b1 = bih1[row] + bhh1[row];
        cb0[c] = f32x4{b0, b0, b0, b0};
        cb1[c] = f32x4{b1, b1, b1, b1};
        wxa[c] = Wih0[row*3+0]; wxb[c] = Wih0[row*3+1]; wxc[c] = Wih0[row*3+2];
    }

    // x base for this block's single sequence (wave-uniform loads, L2-resident)
    const float* xq = x + (size_t)blockIdx.x * TT * 3;

    float cst0 = 0.0f;   // c-state L0 (elem=col)
    float cst1 = 0.0f;   // c-state L1 (elem=col)

    __syncthreads();

    for (int it = 0; it <= TT; ++it) {
        const int cur  = it & 1;
        const int prev = cur ^ 1;

        // shared A-frags: h1[it-1] (row 0 replicated; 16B wave-broadcast reads)
        const _Float16* hb1 = h1a[prev] + quad * 8;
        half8 a0 = *(const half8*)hb1;
        half8 a1 = *(const half8*)(hb1 + 32);

        if (it < TT) {
            const float* xp = xq + it * 3;
            const float x0 = xp[0], x1 = xp[1], x2 = xp[2];

            f32x4 acc[4];
            #pragma unroll
            for (int c = 0; c < 4; ++c) {
                f32x4 z = cb0[c];        // bias pre-loaded into accumulator
                z = __builtin_amdgcn_mfma_f32_16x16x32_f16(a0, w0[c][0], z, 0, 0, 0);
                z = __builtin_amdgcn_mfma_f32_16x16x32_f16(a1, w0[c][1], z, 0, 0, 0);
                acc[c] = z;
            }
            // M=1: all C/D regs identical -> read reg 0
            float pi = acc[0][0] + wxa[0]*x0 + wxb[0]*x1 + wxc[0]*x2;
            float pf = acc[1][0] + wxa[1]*x0 + wxb[1]*x1 + wxc[1]*x2;
            float pg = acc[2][0] + wxa[2]*x0 + wxb[2]*x1 + wxc[2]*x2;
            float po = acc[3][0] + wxa[3]*x0 + wxb[3]*x1 + wxc[3]*x2;
            float iv = fast_sigmoid(pi), fv = fast_sigmoid(pf);
            float gv = fast_tanh(pg),    ov = fast_sigmoid(po);
            cst0 = fmaf(fv, cst0, iv * gv);
            if (quad == 0)
                h1a[cur][col] = (_Float16)(ov * fast_tanh(cst0));   // h1[it]
        }

        if (it >= 1) {
            // L1 step it-1: K 0..63 = h1[it-1] (a0,a1); K 64..127 = h2[it-2]@cur
            const _Float16* hb2 = h2a[cur] + quad * 8;
            half8 a2 = *(const half8*)hb2;
            half8 a3 = *(const half8*)(hb2 + 32);
            f32x4 acc[4];
            #pragma unroll
            for (int c = 0; c < 4; ++c) {
                f32x4 z = cb1[c];
                z = __builtin_amdgcn_mfma_f32_16x16x32_f16(a0, w1[c][0], z, 0, 0, 0);
                z = __builtin_amdgcn_mfma_f32_16x16x32_f16(a1, w1[c][1], z, 0, 0, 0);
                z = __builtin_amdgcn_mfma_f32_16x16x32_f16(a2, w1[c][2], z, 0, 0, 0);
                z = __builtin_amdgcn_mfma_f32_16x16x32_f16(a3, w1[c][3], z, 0, 0, 0);
                acc[c] = z;
            }
            float pi = acc[0][0];
            float pf = acc[1][0];
            float pg = acc[2][0];
            float po = acc[3][0];
            float iv = fast_sigmoid(pi), fv = fast_sigmoid(pf);
            float gv = fast_tanh(pg),    ov = fast_sigmoid(po);
            cst1 = fmaf(fv, cst1, iv * gv);
            float hv = ov * fast_tanh(cst1);
            if (quad == 0) {
                h2a[prev][col] = (_Float16)hv;                      // h2[it-1]
                if (it == TT)
                    out[(size_t)blockIdx.x * 64 + col] = hv;
            }
        }
        __syncthreads();
    }
}

extern "C" void kernel_launch(void* const* d_in, const int* in_sizes, int n_in,
                              void* d_out, int out_size, void* d_ws, size_t ws_size,
                              hipStream_t stream) {
    const float* x    = (const float*)d_in[0];
    const float* Wih0 = (const float*)d_in[1];
    const float* Whh0 = (const float*)d_in[2];
    const float* bih0 = (const float*)d_in[3];
    const float* bhh0 = (const float*)d_in[4];
    const float* Wih1 = (const float*)d_in[5];
    const float* Whh1 = (const float*)d_in[6];
    const float* bih1 = (const float*)d_in[7];
    const float* bhh1 = (const float*)d_in[8];
    float* out = (float*)d_out;

    // 512 sequences, 1 per block -> 512 blocks = 2 blocks/CU; 256 threads
    // (4 balanced waves) -> 2 waves/SIMD of independent per-block pipelines.
    lstm2_fused<<<512, 256, 0, stream>>>(x, Wih0, Whh0, bih0, bhh0,
                                         Wih1, Whh1, bih1, bhh1, out);
}

// Round 17
// 1341.828 us; speedup vs baseline: 1.6877x; 1.6877x over previous
//
#include <hip/hip_runtime.h>
#include <math.h>

// BiometricLSTM: 2-layer LSTM, B=512, T=2048, I=3, H=64, fp32 in/out. Output = final h2 (B,64).
//
// R17: R13 (best, 1392 us) with the L1 pole shortened. R14/R15/R16 triangle
// proved: split waves with small weight sets (no register-motion tax, VGPR=68)
// at 2 waves/SIMD is the arrangement optimum; merged waves (96 weight VGPRs)
// saturate issue with copy traffic. So keep R13's shape and attack its critical
// wave: L1 had 16 MFMA; its Wih1.h1 half uses the SAME A-frags L0 already loads.
// Move Wih1 into L0 waves (8 extra MFMA, 0 extra LDS reads), deepen L1's lag to
// 2 steps so the partial hand-off crosses a barrier:
//   iter it: L0 computes step it (Whh0 gates + update) AND pI(it-1)=Wih1.h1[it-1]
//            -> pIbuf[(it-1)&1];
//            L1 computes step it-2: Whh1.h2[it-3] (8 MFMA, bias in C) + pI(it-2)
//            (read pIbuf[(it-2)&1], opposite parity of this iter's write) + update.
// Parities verified: h1[t]@t&1 (unchanged); h2[t]@t&1 (write h2a[cur]=h2[it-2],
// read h2a[prev]=h2[it-3]); pIbuf double-buffered by step parity, write@prev /
// read@cur disjoint. Loop to TT+1; L1 outputs step TT-1 at it=TT+1.
// All else R13 verbatim: 128 blocks x 512 thr, M=4 replicated rows (A row =
// (l16&3)*HSTR), quad-selected in-lane update, HSTR=80 (0 conflicts), x
// prefetch, ONE barrier/iter, f16 weights/h + f32 accum.

typedef _Float16 half8 __attribute__((ext_vector_type(8)));
typedef float    f32x4 __attribute__((ext_vector_type(4)));

constexpr int TT = 2048;
constexpr int HSTR = 80;   // h row stride in halves (160 B)

__device__ __forceinline__ float fast_sigmoid(float x) {
    return 1.0f / (1.0f + __expf(-x));
}
// tanh = 1 - 2/(exp(2x)+1): saturates correctly at +-inf
__device__ __forceinline__ float fast_tanh(float x) {
    return 1.0f - 2.0f / (__expf(2.0f * x) + 1.0f);
}
// select component q (lane's quad) from an f32x4 accumulator
__device__ __forceinline__ float sel4(f32x4 v, int q) {
    float r = v[0];
    r = (q == 1) ? v[1] : r;
    r = (q == 2) ? v[2] : r;
    r = (q == 3) ? v[3] : r;
    return r;
}

__global__ __launch_bounds__(512) void lstm2_fused(
    const float* __restrict__ x,
    const float* __restrict__ Wih0, const float* __restrict__ Whh0,
    const float* __restrict__ bih0, const float* __restrict__ bhh0,
    const float* __restrict__ Wih1, const float* __restrict__ Whh1,
    const float* __restrict__ bih1, const float* __restrict__ bhh1,
    float* __restrict__ out)
{
    __shared__ __align__(16) _Float16 h1a[2][4 * HSTR];   // [parity][seq*HSTR + elem]
    __shared__ __align__(16) _Float16 h2a[2][4 * HSTR];
    __shared__ __align__(16) float4   pIbuf[2][4][64];    // [stepParity][class][col] = 4 seqs

    const int tid  = threadIdx.x;
    const int lane = tid & 63;
    const int wid  = tid >> 6;
    const int quad = lane >> 4;
    const int l16  = lane & 15;
    const bool isL1 = (wid >= 4);
    const int col  = (wid & 3) * 16 + l16;   // gate-elem column this lane owns per class

    // ---- zero h double-buffers ----
    for (int i = tid; i < 2 * 4 * HSTR; i += 512) {
        ((_Float16*)h1a)[i] = (_Float16)0.0f;
        ((_Float16*)h2a)[i] = (_Float16)0.0f;
    }

    // ---- weights (B-frags, f16): lane holds W[c*64+col][f*32 + quad*8 .. +8] ----
    half8 wA[4][2];      // L0 waves: Whh0 | L1 waves: Whh1
    half8 wB[4][2];      // L0 waves only: Wih1
    f32x4 cbias[4];      // bias splat, MFMA C-init (L0: bias0; L1: bias1)
    float wxa[4], wxb[4], wxc[4];            // L0 only
    #pragma unroll
    for (int c = 0; c < 4; ++c) {
        const int row = c * 64 + col;
        if (!isL1) {
            #pragma unroll
            for (int f = 0; f < 2; ++f) {
                const float* p = Whh0 + (size_t)row * 64 + f * 32 + quad * 8;
                half8 h;
                #pragma unroll
                for (int u = 0; u < 8; ++u) h[u] = (_Float16)p[u];
                wA[c][f] = h;
                const float* q = Wih1 + (size_t)row * 64 + f * 32 + quad * 8;
                half8 g;
                #pragma unroll
                for (int u = 0; u < 8; ++u) g[u] = (_Float16)q[u];
                wB[c][f] = g;
            }
            const float b = bih0[row] + bhh0[row];
            cbias[c] = f32x4{b, b, b, b};
            wxa[c] = Wih0[row*3+0]; wxb[c] = Wih0[row*3+1]; wxc[c] = Wih0[row*3+2];
        } else {
            #pragma unroll
            for (int f = 0; f < 2; ++f) {
                const float* p = Whh1 + (size_t)row * 64 + f * 32 + quad * 8;
                half8 h;
                #pragma unroll
                for (int u = 0; u < 8; ++u) h[u] = (_Float16)p[u];
                wA[c][f] = h;
            }
            const float b = bih1[row] + bhh1[row];
            cbias[c] = f32x4{b, b, b, b};
        }
    }

    // ---- x prefetch (L0 waves): this lane's seq = quad ----
    const float* xq = x + (size_t)(blockIdx.x * 4 + quad) * TT * 3;
    float xn0 = 0.f, xn1 = 0.f, xn2 = 0.f;
    if (!isL1) { xn0 = xq[0]; xn1 = xq[1]; xn2 = xq[2]; }

    float cst = 0.0f;    // cell state (layer per role, seq=quad, elem=col)

    __syncthreads();

    // iter it = 0 .. TT+1. L0: step it (it<TT) + pI(it-1) (it<=TT).
    // L1: step it-2 (it>=2). ONE barrier per iteration.
    for (int it = 0; it <= TT + 1; ++it) {
        const int cur  = it & 1;
        const int prev = cur ^ 1;

        if (!isL1) {
            if (it <= TT) {
                // A-frags: h1[it-1] (parity prev), replicated rows
                const _Float16* hb = h1a[prev] + (l16 & 3) * HSTR + quad * 8;
                half8 a0 = *(const half8*)hb;
                half8 a1 = *(const half8*)(hb + 32);

                // pI(it-1) = Wih1 . h1[it-1]  -> pIbuf[(it-1)&1] == [prev]
                f32x4 accP[4];
                #pragma unroll
                for (int c = 0; c < 4; ++c) {
                    f32x4 z = {0.f, 0.f, 0.f, 0.f};
                    z = __builtin_amdgcn_mfma_f32_16x16x32_f16(a0, wB[c][0], z, 0, 0, 0);
                    z = __builtin_amdgcn_mfma_f32_16x16x32_f16(a1, wB[c][1], z, 0, 0, 0);
                    accP[c] = z;
                }
                if (quad == 0) {
                    #pragma unroll
                    for (int c = 0; c < 4; ++c)
                        pIbuf[prev][c][col] = make_float4(accP[c][0], accP[c][1],
                                                          accP[c][2], accP[c][3]);
                }

                if (it < TT) {
                    // L0 gates: Whh0 . h1[it-1] + bias (in C) + x-proj
                    const float x0 = xn0, x1 = xn1, x2 = xn2;
                    const int nt = (it + 1 < TT) ? it + 1 : TT - 1;
                    const float* np = xq + nt * 3;
                    xn0 = np[0]; xn1 = np[1]; xn2 = np[2];

                    f32x4 acc[4];
                    #pragma unroll
                    for (int c = 0; c < 4; ++c) {
                        f32x4 z = cbias[c];
                        z = __builtin_amdgcn_mfma_f32_16x16x32_f16(a0, wA[c][0], z, 0, 0, 0);
                        z = __builtin_amdgcn_mfma_f32_16x16x32_f16(a1, wA[c][1], z, 0, 0, 0);
                        acc[c] = z;
                    }
                    float pi = sel4(acc[0], quad) + wxa[0]*x0 + wxb[0]*x1 + wxc[0]*x2;
                    float pf = sel4(acc[1], quad) + wxa[1]*x0 + wxb[1]*x1 + wxc[1]*x2;
                    float pg = sel4(acc[2], quad) + wxa[2]*x0 + wxb[2]*x1 + wxc[2]*x2;
                    float po = sel4(acc[3], quad) + wxa[3]*x0 + wxb[3]*x1 + wxc[3]*x2;
                    float iv = fast_sigmoid(pi), fv = fast_sigmoid(pf);
                    float gv = fast_tanh(pg),    ov = fast_sigmoid(po);
                    cst = fmaf(fv, cst, iv * gv);
                    h1a[cur][quad * HSTR + col] = (_Float16)(ov * fast_tanh(cst)); // h1[it]
                }
            }
        } else {
            if (it >= 2) {
                // L1 step s = it-2: Whh1 . h2[it-3] (parity prev) + pI(s) (pIbuf[cur])
                const _Float16* hb2 = h2a[prev] + (l16 & 3) * HSTR + quad * 8;
                half8 a2 = *(const half8*)hb2;
                half8 a3 = *(const half8*)(hb2 + 32);
                f32x4 acc[4];
                #pragma unroll
                for (int c = 0; c < 4; ++c) {
                    f32x4 z = cbias[c];
                    z = __builtin_amdgcn_mfma_f32_16x16x32_f16(a2, wA[c][0], z, 0, 0, 0);
                    z = __builtin_amdgcn_mfma_f32_16x16x32_f16(a3, wA[c][1], z, 0, 0, 0);
                    acc[c] = z;
                }
                // partial: pIbuf[cur][c][col][seq=quad]  (contiguous b32, <=2-way banks)
                const float* pb = (const float*)&pIbuf[cur][0][col] + quad;
                float pi = sel4(acc[0], quad) + pb[0 * 256];
                float pf = sel4(acc[1], quad) + pb[1 * 256];
                float pg = sel4(acc[2], quad) + pb[2 * 256];
                float po = sel4(acc[3], quad) + pb[3 * 256];
                float iv = fast_sigmoid(pi), fv = fast_sigmoid(pf);
                float gv = fast_tanh(pg),    ov = fast_sigmoid(po);
                cst = fmaf(fv, cst, iv * gv);
                float hv = ov * fast_tanh(cst);
                h2a[cur][quad * HSTR + col] = (_Float16)hv;            // h2[it-2]
                if (it == TT + 1)
                    out[(size_t)(blockIdx.x * 4 + quad) * 64 + col] = hv;
            }
        }
        __syncthreads();
    }
}

extern "C" void kernel_launch(void* const* d_in, const int* in_sizes, int n_in,
                              void* d_out, int out_size, void* d_ws, size_t ws_size,
                              hipStream_t stream) {
    const float* x    = (const float*)d_in[0];
    const float* Wih0 = (const float*)d_in[1];
    const float* Whh0 = (const float*)d_in[2];
    const float* bih0 = (const float*)d_in[3];
    const float* bhh0 = (const float*)d_in[4];
    const float* Wih1 = (const float*)d_in[5];
    const float* Whh1 = (const float*)d_in[6];
    const float* bih1 = (const float*)d_in[7];
    const float* bhh1 = (const float*)d_in[8];
    float* out = (float*)d_out;

    // 512 sequences / 4 per block = 128 blocks; 512 threads (8 waves, 2/SIMD).
    lstm2_fused<<<128, 512, 0, stream>>>(x, Wih0, Whh0, bih0, bhh0,
                                         Wih1, Whh1, bih1, bhh1, out);
}